// Round 4
// baseline (235.815 us; speedup 1.0000x reference)
//
#include <hip/hip_runtime.h>
#include <math.h>

#define N_NODES 60000
#define M1_N    40000
#define M2_N    40000
#define DD      64
#define S0_N    10
#define S1_N    20
#define R_TOTAL (N_NODES + M1_N + M2_N)

typedef __attribute__((ext_vector_type(8))) short short8;   // 8 bf16 = 4 VGPRs
typedef __attribute__((ext_vector_type(4))) float f32x4;

__device__ __forceinline__ float wave_sum(float x) {
#pragma unroll
    for (int o = 32; o >= 1; o >>= 1) x += __shfl_xor(x, o, 64);
    return x;
}
__device__ __forceinline__ float bcast(float v, int l) {
    return __uint_as_float(__builtin_amdgcn_readlane(__float_as_uint(v), l));
}
__device__ __forceinline__ float tanh_fast(float x) {
    return 1.f - 2.f / (__expf(2.f * x) + 1.f);
}
// f32 -> bf16 with round-to-nearest-even
__device__ __forceinline__ unsigned short f2bf(float x) {
    unsigned u = __float_as_uint(x);
    return (unsigned short)((u + 0x7FFFu + ((u >> 16) & 1u)) >> 16);
}
__device__ __forceinline__ float bf2f(unsigned short u) {
    return __uint_as_float(((unsigned)u) << 16);
}
__device__ __forceinline__ float dot4(float4 a, float4 b) {
    return fmaf(a.x, b.x, fmaf(a.y, b.y, fmaf(a.z, b.z, a.w * b.w)));
}

// Kernel 1: per-row projections + global-softmax reduction.
// 4 rows per wave per iteration: lane l -> row (l>>4), dims 4*(l&15)+j.
// 16-lane butterflies (4 steps) instead of full-wave (6 steps); float4 loads.
__global__ __launch_bounds__(256) void k_proj(
    const float* __restrict__ h0, const float* __restrict__ h1, const float* __restrict__ h2,
    const float* __restrict__ aw0, const float* __restrict__ aw1, const float* __restrict__ gatt,
    float* __restrict__ accum,
    float* __restrict__ p0r0, float* __restrict__ p0r1,
    float* __restrict__ p1, float* __restrict__ p2,
    unsigned short* __restrict__ h1bf, unsigned short* __restrict__ h2bf)
{
    __shared__ float s_wsum[64];
    __shared__ float s_se;
    const int tid = threadIdx.x, lane = tid & 63, wid = tid >> 6;
    if (tid < 64) s_wsum[tid] = 0.f;
    if (tid == 0) s_se = 0.f;
    __syncthreads();

    const int sub = lane & 15;            // float4 slot within the row
    const int rowin = lane >> 4;          // which of the 4 rows
    const float4 g4   = ((const float4*)gatt)[sub];
    const float4 a0r4 = ((const float4*)aw0)[sub];
    const float4 a1r4 = ((const float4*)aw1)[sub];
    const float4 a0n4 = ((const float4*)aw0)[16 + sub];
    const float4 a1n4 = ((const float4*)aw1)[16 + sub];

    float4 wsum4 = make_float4(0.f, 0.f, 0.f, 0.f);
    float r_se = 0.f;

    const int gw = blockIdx.x * 4 + wid;
    const int nw = gridDim.x * 4;
    for (int gidx = gw; gidx < R_TOTAL / 4; gidx += nw) {
        const int r0 = gidx * 4;          // first row of this 4-row group
        const float* srcbase;
        if (r0 < N_NODES)              srcbase = h0 + (size_t)r0 * DD;
        else if (r0 < N_NODES + M1_N)  srcbase = h1 + (size_t)(r0 - N_NODES) * DD;
        else                           srcbase = h2 + (size_t)(r0 - N_NODES - M1_N) * DD;
        const float4 v = ((const float4*)srcbase)[lane];

        // global-att score (16-lane butterfly; result uniform within group)
        float sp = dot4(v, g4);
#pragma unroll
        for (int o = 8; o >= 1; o >>= 1) sp += __shfl_xor(sp, o, 64);
        const float es = __expf(sp * 0.125f);
        r_se += es;                        // counted 16x; scaled at the end
        wsum4.x = fmaf(es, v.x, wsum4.x);
        wsum4.y = fmaf(es, v.y, wsum4.y);
        wsum4.z = fmaf(es, v.z, wsum4.z);
        wsum4.w = fmaf(es, v.w, wsum4.w);

        if (r0 < N_NODES) {
            float q0 = dot4(v, a0r4);
            float q1 = dot4(v, a1r4);
#pragma unroll
            for (int o = 8; o >= 1; o >>= 1) {
                q0 += __shfl_xor(q0, o, 64);
                q1 += __shfl_xor(q1, o, 64);
            }
            if (sub == 0) { p0r0[r0 + rowin] = q0; p0r1[r0 + rowin] = q1; }
        } else if (r0 < N_NODES + M1_N) {
            const int rr0 = r0 - N_NODES;
            float q = dot4(v, a0n4);
#pragma unroll
            for (int o = 8; o >= 1; o >>= 1) q += __shfl_xor(q, o, 64);
            if (sub == 0) p1[rr0 + rowin] = q;
            ushort4 b;
            b.x = f2bf(v.x); b.y = f2bf(v.y); b.z = f2bf(v.z); b.w = f2bf(v.w);
            ((ushort4*)(h1bf + (size_t)rr0 * DD))[lane] = b;
        } else {
            const int rr0 = r0 - N_NODES - M1_N;
            float q = dot4(v, a1n4);
#pragma unroll
            for (int o = 8; o >= 1; o >>= 1) q += __shfl_xor(q, o, 64);
            if (sub == 0) p2[rr0 + rowin] = q;
            ushort4 b;
            b.x = f2bf(v.x); b.y = f2bf(v.y); b.z = f2bf(v.z); b.w = f2bf(v.w);
            ((ushort4*)(h2bf + (size_t)rr0 * DD))[lane] = b;
        }
    }

    // cross-row-group reduce (lanes l, l^16, l^32, l^48 hold the same dims)
#pragma unroll
    for (int o = 16; o <= 32; o <<= 1) {
        wsum4.x += __shfl_xor(wsum4.x, o, 64);
        wsum4.y += __shfl_xor(wsum4.y, o, 64);
        wsum4.z += __shfl_xor(wsum4.z, o, 64);
        wsum4.w += __shfl_xor(wsum4.w, o, 64);
    }
    const float se = wave_sum(r_se) * (1.f / 16.f);   // es was counted by 16 lanes
    if (lane < 16) {
        atomicAdd(&s_wsum[lane * 4 + 0], wsum4.x);
        atomicAdd(&s_wsum[lane * 4 + 1], wsum4.y);
        atomicAdd(&s_wsum[lane * 4 + 2], wsum4.z);
        atomicAdd(&s_wsum[lane * 4 + 3], wsum4.w);
    }
    if (lane == 0) atomicAdd(&s_se, se);
    __syncthreads();
    if (tid < 64) atomicAdd(&accum[4 + tid], s_wsum[tid]);
    if (tid == 0) atomicAdd(&accum[2], s_se);
}

// Kernel 2: per-node neighbor attention. One wave per node, lane = dim.
// Both softmaxes share one 5-step half-wave butterfly (w0 lanes 0..9, w1 lanes 32..51).
// All 30 bf16 row-gathers issued before reduction. e0/e1 stored bf16.
__global__ __launch_bounds__(256) void k_attn(
    const unsigned short* __restrict__ h1bf, const unsigned short* __restrict__ h2bf,
    const int* __restrict__ nei0, const int* __restrict__ nei1,
    const float* __restrict__ p0r0, const float* __restrict__ p0r1,
    const float* __restrict__ p1, const float* __restrict__ p2,
    unsigned short* __restrict__ e0bf, unsigned short* __restrict__ e1bf)
{
    const int tid = threadIdx.x, lane = tid & 63, wid = tid >> 6;
    const bool grp0 = (lane < S0_N);
    const bool grp1 = (lane >= 32) && (lane < 32 + S1_N);
    const int gw = blockIdx.x * 4 + wid;
    const int nw = gridDim.x * 4;
    for (int n = gw; n < N_NODES; n += nw) {
        const float pr0 = p0r0[n];
        const float pr1 = p0r1[n];

        int idx = 0; float w = 0.f;
        if (grp0) idx = nei0[n * S0_N + lane];
        if (grp1) idx = nei1[n * S1_N + (lane - 32)];
        if (grp0 | grp1) {
            float t = (grp0 ? pr0 : pr1) + (grp0 ? p1[idx] : p2[idx]);
            t = (t >= 0.f) ? t : 0.01f * t;      // leaky_relu(0.01)
            w = __expf(t);                        // scores bounded; no max-sub
        }
        float sv = w;
#pragma unroll
        for (int o = 16; o >= 1; o >>= 1) sv += __shfl_xor(sv, o, 64);
        const float inv0 = 1.f / bcast(sv, 0);
        const float inv1 = 1.f / bcast(sv, 32);

        // issue all 30 gathers (independent -> in flight together)
        float v0[S0_N], v1[S1_N];
#pragma unroll
        for (int s = 0; s < S0_N; s++) {
            const int i0 = __builtin_amdgcn_readlane(idx, s);
            v0[s] = bf2f(h1bf[i0 * DD + lane]);
        }
#pragma unroll
        for (int s = 0; s < S1_N; s++) {
            const int i1 = __builtin_amdgcn_readlane(idx, 32 + s);
            v1[s] = bf2f(h2bf[i1 * DD + lane]);
        }

        {
            float ea = 0.f, eb = 0.f;
#pragma unroll
            for (int s = 0; s < S0_N; s += 2) {
                ea = fmaf(bcast(w, s),     v0[s],     ea);
                eb = fmaf(bcast(w, s + 1), v0[s + 1], eb);
            }
            float e = (ea + eb) * inv0;
            e = (e > 0.f) ? e : (__expf(e) - 1.f);   // ELU
            e0bf[n * DD + lane] = f2bf(e);
        }
        {
            float ea = 0.f, eb = 0.f, ec = 0.f, ed = 0.f;
#pragma unroll
            for (int s = 0; s < S1_N; s += 4) {
                ea = fmaf(bcast(w, 32 + s),     v1[s],     ea);
                eb = fmaf(bcast(w, 33 + s),     v1[s + 1], eb);
                ec = fmaf(bcast(w, 34 + s),     v1[s + 2], ec);
                ed = fmaf(bcast(w, 35 + s),     v1[s + 3], ed);
            }
            float e = ((ea + eb) + (ec + ed)) * inv1;
            e = (e > 0.f) ? e : (__expf(e) - 1.f);
            e1bf[n * DD + lane] = f2bf(e);
        }
    }
}

// Kernel 3: beta reduction via MFMA. Per 16-node tile: T = E_tile @ fcw^T via
// 16x16x32_bf16 (4 col-tiles x 2 K-halves), then tanh, dot with fus, reduce.
__global__ __launch_bounds__(256) void k_beta(
    const unsigned short* __restrict__ e0bf, const unsigned short* __restrict__ e1bf,
    const float* __restrict__ fcw, const float* __restrict__ fcb,
    const float* __restrict__ fus, float* __restrict__ accum)
{
    __shared__ float s_part[2];
    const int tid = threadIdx.x, lane = tid & 63, wid = tid >> 6;
    if (tid < 2) s_part[tid] = 0.f;
    const int m = lane & 15, q = lane >> 4;

    short8 bfr[4][2];          // B-frag: lane holds fcw[n=t*16+m][k = h*32 + q*8 + j]
    float fb[4], fu[4];
#pragma unroll
    for (int t = 0; t < 4; t++) {
        const float* wrow = fcw + (t * 16 + m) * DD;
#pragma unroll
        for (int h = 0; h < 2; h++) {
            const float* p = wrow + h * 32 + q * 8;
#pragma unroll
            for (int j = 0; j < 8; j++) bfr[t][h][j] = (short)f2bf(p[j]);
        }
        fb[t] = fcb[t * 16 + m];
        fu[t] = fus[t * 16 + m];
    }
    __syncthreads();

    float rb0 = 0.f, rb1 = 0.f;
    const int gw = blockIdx.x * 4 + wid;
    const int nw = gridDim.x * 4;
    for (int tile = gw; tile < N_NODES / 16; tile += nw) {
        const int rowbase = (tile * 16 + m) * DD + q * 8;  // A-frag: E[m][k=q*8+j]
        {
            const short8 a0 = *(const short8*)(e0bf + rowbase);
            const short8 a1 = *(const short8*)(e0bf + rowbase + 32);
            f32x4 c[4];
#pragma unroll
            for (int t = 0; t < 4; t++) {
                c[t] = f32x4{0.f, 0.f, 0.f, 0.f};
                c[t] = __builtin_amdgcn_mfma_f32_16x16x32_bf16(a0, bfr[t][0], c[t], 0, 0, 0);
                c[t] = __builtin_amdgcn_mfma_f32_16x16x32_bf16(a1, bfr[t][1], c[t], 0, 0, 0);
            }
#pragma unroll
            for (int t = 0; t < 4; t++)
#pragma unroll
                for (int j = 0; j < 4; j++)
                    rb0 += tanh_fast(c[t][j] + fb[t]) * fu[t];
        }
        {
            const short8 a0 = *(const short8*)(e1bf + rowbase);
            const short8 a1 = *(const short8*)(e1bf + rowbase + 32);
            f32x4 c[4];
#pragma unroll
            for (int t = 0; t < 4; t++) {
                c[t] = f32x4{0.f, 0.f, 0.f, 0.f};
                c[t] = __builtin_amdgcn_mfma_f32_16x16x32_bf16(a0, bfr[t][0], c[t], 0, 0, 0);
                c[t] = __builtin_amdgcn_mfma_f32_16x16x32_bf16(a1, bfr[t][1], c[t], 0, 0, 0);
            }
#pragma unroll
            for (int t = 0; t < 4; t++)
#pragma unroll
                for (int j = 0; j < 4; j++)
                    rb1 += tanh_fast(c[t][j] + fb[t]) * fu[t];
        }
    }
    const float b0 = wave_sum(rb0);
    const float b1 = wave_sum(rb1);
    if (lane == 0) { atomicAdd(&s_part[0], b0); atomicAdd(&s_part[1], b1); }
    __syncthreads();
    if (tid == 0) { atomicAdd(&accum[0], s_part[0]); atomicAdd(&accum[1], s_part[1]); }
}

// Kernel 4: final elementwise combine (bf16 e reads, f32 out).
__global__ __launch_bounds__(256) void k_out(
    const unsigned short* __restrict__ e0bf, const unsigned short* __restrict__ e1bf,
    const float* __restrict__ accum, const float* __restrict__ gate,
    float* __restrict__ out)
{
    const int i = blockIdx.x * 256 + threadIdx.x;   // float4 index, exact grid
    const float b0 = accum[0] * (1.f / N_NODES);
    const float b1 = accum[1] * (1.f / N_NODES);
    const float mx = fmaxf(b0, b1);
    const float eb0 = __expf(b0 - mx), eb1 = __expf(b1 - mx);
    const float gv  = 1.f / (1.f + __expf(-gate[0]));
    const float c0  = gv * eb0 / (eb0 + eb1);
    const float c1  = gv * eb1 / (eb0 + eb1);
    const float cg  = (1.f - gv) / accum[2];

    const float4 av = ((const float4*)(accum + 4))[i & 15];
    const ushort4 ua = ((const ushort4*)e0bf)[i];
    const ushort4 ub = ((const ushort4*)e1bf)[i];
    float4 o;
    o.x = c0 * bf2f(ua.x) + c1 * bf2f(ub.x) + cg * av.x;
    o.y = c0 * bf2f(ua.y) + c1 * bf2f(ub.y) + cg * av.y;
    o.z = c0 * bf2f(ua.z) + c1 * bf2f(ub.z) + cg * av.z;
    o.w = c0 * bf2f(ua.w) + c1 * bf2f(ub.w) + cg * av.w;
    ((float4*)out)[i] = o;
}

extern "C" void kernel_launch(void* const* d_in, const int* in_sizes, int n_in,
                              void* d_out, int out_size, void* d_ws, size_t ws_size,
                              hipStream_t stream) {
    (void)in_sizes; (void)n_in; (void)out_size; (void)ws_size;
    const float* h0   = (const float*)d_in[0];
    const float* h1   = (const float*)d_in[1];
    const float* h2   = (const float*)d_in[2];
    const int*   nei0 = (const int*)  d_in[3];
    const int*   nei1 = (const int*)  d_in[4];
    const float* aw0  = (const float*)d_in[5];
    const float* aw1  = (const float*)d_in[6];
    const float* fcw  = (const float*)d_in[7];
    const float* fcb  = (const float*)d_in[8];
    const float* fus  = (const float*)d_in[9];
    const float* gatt = (const float*)d_in[10];
    const float* gate = (const float*)d_in[11];
    float* out = (float*)d_out;

    // workspace layout (float offsets; bf16 areas cast to ushort*)
    float* ws    = (float*)d_ws;
    float* accum = ws;                               // [0]=b0 [1]=b1 [2]=sumexp [4..67]=wsum
    float* p0r0  = ws + 256;                         // N
    float* p0r1  = p0r0 + N_NODES;                   // N
    float* p1    = p0r1 + N_NODES;                   // M1
    float* p2    = p1 + M1_N;                        // M2
    unsigned short* h1bf = (unsigned short*)(p2 + M2_N);            // M1*64 bf16
    unsigned short* h2bf = h1bf + (size_t)M1_N * DD;                // M2*64 bf16
    unsigned short* e0bf = h2bf + (size_t)M2_N * DD;                // N*64 bf16
    unsigned short* e1bf = e0bf + (size_t)N_NODES * DD;             // N*64 bf16

    hipMemsetAsync(accum, 0, 256 * sizeof(float), stream);
    k_proj<<<2048, 256, 0, stream>>>(h0, h1, h2, aw0, aw1, gatt, accum,
                                     p0r0, p0r1, p1, p2, h1bf, h2bf);
    k_attn<<<2048, 256, 0, stream>>>(h1bf, h2bf, nei0, nei1, p0r0, p0r1, p1, p2, e0bf, e1bf);
    k_beta<<<512, 256, 0, stream>>>(e0bf, e1bf, fcw, fcb, fus, accum);
    k_out<<<(N_NODES * DD / 4) / 256, 256, 0, stream>>>(e0bf, e1bf, accum, gate, out);
}

// Round 5
// 204.528 us; speedup vs baseline: 1.1530x; 1.1530x over previous
//
#include <hip/hip_runtime.h>
#include <math.h>

#define N_NODES 60000
#define M1_N    40000
#define M2_N    40000
#define DD      64
#define S0_N    10
#define S1_N    20
#define R_TOTAL (N_NODES + M1_N + M2_N)
#define T_H0    (N_NODES / 16)              // 3750 tiles
#define T_H1    (T_H0 + M1_N / 16)          // 6250
#define T_ALL   (T_H1 + M2_N / 16)          // 8750

typedef __attribute__((ext_vector_type(8))) short short8;   // 8 bf16 = 4 VGPRs
typedef __attribute__((ext_vector_type(4))) float f32x4;

__device__ __forceinline__ float wave_sum(float x) {
#pragma unroll
    for (int o = 32; o >= 1; o >>= 1) x += __shfl_xor(x, o, 64);
    return x;
}
__device__ __forceinline__ float bcast(float v, int l) {
    return __uint_as_float(__builtin_amdgcn_readlane(__float_as_uint(v), l));
}
__device__ __forceinline__ float tanh_fast(float x) {
    return 1.f - 2.f / (__expf(2.f * x) + 1.f);
}
// f32 -> bf16 round-to-nearest-even
__device__ __forceinline__ unsigned short f2bf(float x) {
    unsigned u = __float_as_uint(x);
    return (unsigned short)((u + 0x7FFFu + ((u >> 16) & 1u)) >> 16);
}
__device__ __forceinline__ float bf2f(unsigned short u) {
    return __uint_as_float(((unsigned)u) << 16);
}

// Kernel 1: projections + global softmax via MFMA. One wave = 16-row tile.
// A = rows (bf16, also emitted as h1bf/h2bf), B cols = {g, a0r, a1r, a0n, a1n}.
// No cross-lane reduction inside the loop; es transposed via wave-sync LDS.
__global__ __launch_bounds__(256) void k_proj(
    const float* __restrict__ h0, const float* __restrict__ h1, const float* __restrict__ h2,
    const float* __restrict__ aw0, const float* __restrict__ aw1, const float* __restrict__ gatt,
    float* __restrict__ accum,
    float* __restrict__ p0r0, float* __restrict__ p0r1,
    float* __restrict__ p1, float* __restrict__ p2,
    unsigned short* __restrict__ h1bf, unsigned short* __restrict__ h2bf)
{
    __shared__ float s_wsum[64];
    __shared__ float s_se;
    __shared__ float s_es[4][16];
    const int tid = threadIdx.x, lane = tid & 63, wid = tid >> 6;
    if (tid < 64) s_wsum[tid] = 0.f;
    if (tid == 0) s_se = 0.f;
    __syncthreads();

    const int m = lane & 15, quad = lane >> 4;

    // B-frag: col n = m; k = quad*8+j (half0) / 32+quad*8+j (half1)
    short8 b0, b1;
    {
        const float* vsel = 0;
        if (m == 1) vsel = aw0;
        else if (m == 2) vsel = aw1;
        else if (m == 3) vsel = aw0 + DD;
        else if (m == 4) vsel = aw1 + DD;
        else if (m == 0) vsel = gatt;
#pragma unroll
        for (int j = 0; j < 8; j++) {
            b0[j] = vsel ? (short)f2bf(vsel[quad * 8 + j]) : (short)0;
            b1[j] = vsel ? (short)f2bf(vsel[32 + quad * 8 + j]) : (short)0;
        }
    }

    float wacc0[8], wacc1[8];
#pragma unroll
    for (int j = 0; j < 8; j++) { wacc0[j] = 0.f; wacc1[j] = 0.f; }
    float r_se = 0.f;

    const int gw = blockIdx.x * 4 + wid, nw = gridDim.x * 4;
    for (int tile = gw; tile < T_ALL; tile += nw) {
        const float* src; int rbase, region;
        if (tile < T_H0)      { src = h0; rbase = tile * 16;          region = 0; }
        else if (tile < T_H1) { src = h1; rbase = (tile - T_H0) * 16; region = 1; }
        else                  { src = h2; rbase = (tile - T_H1) * 16; region = 2; }
        const int row = rbase + m;
        const float4* rpa = (const float4*)(src + (size_t)row * DD + quad * 8);
        const float4* rpb = (const float4*)(src + (size_t)row * DD + 32 + quad * 8);
        const float4 va = rpa[0], vb = rpa[1];   // dims quad*8 .. quad*8+7
        const float4 vc = rpb[0], vd = rpb[1];   // dims 32+quad*8 .. +7

        short8 a0, a1;
        a0[0] = (short)f2bf(va.x); a0[1] = (short)f2bf(va.y);
        a0[2] = (short)f2bf(va.z); a0[3] = (short)f2bf(va.w);
        a0[4] = (short)f2bf(vb.x); a0[5] = (short)f2bf(vb.y);
        a0[6] = (short)f2bf(vb.z); a0[7] = (short)f2bf(vb.w);
        a1[0] = (short)f2bf(vc.x); a1[1] = (short)f2bf(vc.y);
        a1[2] = (short)f2bf(vc.z); a1[3] = (short)f2bf(vc.w);
        a1[4] = (short)f2bf(vd.x); a1[5] = (short)f2bf(vd.y);
        a1[6] = (short)f2bf(vd.z); a1[7] = (short)f2bf(vd.w);

        f32x4 c = {0.f, 0.f, 0.f, 0.f};
        c = __builtin_amdgcn_mfma_f32_16x16x32_bf16(a0, b0, c, 0, 0, 0);
        c = __builtin_amdgcn_mfma_f32_16x16x32_bf16(a1, b1, c, 0, 0, 0);
        // D[row=quad*4+r][col=m]

        if (m == 0) {        // global-att scores -> es, transposed via LDS
            float4 e4;
            e4.x = __expf(c[0] * 0.125f); e4.y = __expf(c[1] * 0.125f);
            e4.z = __expf(c[2] * 0.125f); e4.w = __expf(c[3] * 0.125f);
            *(float4*)&s_es[wid][quad * 4] = e4;
        }
        __builtin_amdgcn_wave_barrier();   // in-order DS pipe: same-wave write->read safe
        const float es = s_es[wid][m];     // es for this lane's row m
        r_se += es;                         // each row counted 4x (quads); scaled below
        wacc0[0] = fmaf(es, va.x, wacc0[0]); wacc0[1] = fmaf(es, va.y, wacc0[1]);
        wacc0[2] = fmaf(es, va.z, wacc0[2]); wacc0[3] = fmaf(es, va.w, wacc0[3]);
        wacc0[4] = fmaf(es, vb.x, wacc0[4]); wacc0[5] = fmaf(es, vb.y, wacc0[5]);
        wacc0[6] = fmaf(es, vb.z, wacc0[6]); wacc0[7] = fmaf(es, vb.w, wacc0[7]);
        wacc1[0] = fmaf(es, vc.x, wacc1[0]); wacc1[1] = fmaf(es, vc.y, wacc1[1]);
        wacc1[2] = fmaf(es, vc.z, wacc1[2]); wacc1[3] = fmaf(es, vc.w, wacc1[3]);
        wacc1[4] = fmaf(es, vd.x, wacc1[4]); wacc1[5] = fmaf(es, vd.y, wacc1[5]);
        wacc1[6] = fmaf(es, vd.z, wacc1[6]); wacc1[7] = fmaf(es, vd.w, wacc1[7]);

        if (region == 0) {
            if (m == 1) { float4 t = {c[0], c[1], c[2], c[3]}; *(float4*)(p0r0 + rbase + quad * 4) = t; }
            if (m == 2) { float4 t = {c[0], c[1], c[2], c[3]}; *(float4*)(p0r1 + rbase + quad * 4) = t; }
        } else if (region == 1) {
            if (m == 3) { float4 t = {c[0], c[1], c[2], c[3]}; *(float4*)(p1 + rbase + quad * 4) = t; }
            *(short8*)(h1bf + (size_t)row * DD + quad * 8) = a0;
            *(short8*)(h1bf + (size_t)row * DD + 32 + quad * 8) = a1;
        } else {
            if (m == 4) { float4 t = {c[0], c[1], c[2], c[3]}; *(float4*)(p2 + rbase + quad * 4) = t; }
            *(short8*)(h2bf + (size_t)row * DD + quad * 8) = a0;
            *(short8*)(h2bf + (size_t)row * DD + 32 + quad * 8) = a1;
        }
    }

    // end-of-kernel reductions only
    r_se *= 0.25f;
#pragma unroll
    for (int o = 1; o <= 8; o <<= 1) {
#pragma unroll
        for (int j = 0; j < 8; j++) {
            wacc0[j] += __shfl_xor(wacc0[j], o, 64);
            wacc1[j] += __shfl_xor(wacc1[j], o, 64);
        }
    }
    if (m == 0) {
#pragma unroll
        for (int j = 0; j < 8; j++) {
            atomicAdd(&s_wsum[quad * 8 + j],      wacc0[j]);
            atomicAdd(&s_wsum[32 + quad * 8 + j], wacc1[j]);
        }
    }
    const float se = wave_sum(r_se);
    if (lane == 0) atomicAdd(&s_se, se);
    __syncthreads();
    if (tid < 64) atomicAdd(&accum[4 + tid], s_wsum[tid]);
    if (tid == 0) atomicAdd(&accum[2], s_se);
}

// Kernel 2: per-node neighbor attention. One wave per node, lane = dim.
__global__ __launch_bounds__(256) void k_attn(
    const unsigned short* __restrict__ h1bf, const unsigned short* __restrict__ h2bf,
    const int* __restrict__ nei0, const int* __restrict__ nei1,
    const float* __restrict__ p0r0, const float* __restrict__ p0r1,
    const float* __restrict__ p1, const float* __restrict__ p2,
    unsigned short* __restrict__ e0bf, unsigned short* __restrict__ e1bf)
{
    const int tid = threadIdx.x, lane = tid & 63, wid = tid >> 6;
    const bool grp0 = (lane < S0_N);
    const bool grp1 = (lane >= 32) && (lane < 32 + S1_N);
    const int gw = blockIdx.x * 4 + wid;
    const int nw = gridDim.x * 4;
    for (int n = gw; n < N_NODES; n += nw) {
        const float pr0 = p0r0[n];
        const float pr1 = p0r1[n];

        int idx = 0; float w = 0.f;
        if (grp0) idx = nei0[n * S0_N + lane];
        if (grp1) idx = nei1[n * S1_N + (lane - 32)];
        if (grp0 | grp1) {
            float t = (grp0 ? pr0 : pr1) + (grp0 ? p1[idx] : p2[idx]);
            t = (t >= 0.f) ? t : 0.01f * t;      // leaky_relu(0.01)
            w = __expf(t);                        // scores bounded; no max-sub
        }
        float sv = w;
#pragma unroll
        for (int o = 16; o >= 1; o >>= 1) sv += __shfl_xor(sv, o, 64);
        const float inv0 = 1.f / bcast(sv, 0);
        const float inv1 = 1.f / bcast(sv, 32);

        float v0[S0_N], v1[S1_N];
#pragma unroll
        for (int s = 0; s < S0_N; s++) {
            const int i0 = __builtin_amdgcn_readlane(idx, s);
            v0[s] = bf2f(h1bf[i0 * DD + lane]);
        }
#pragma unroll
        for (int s = 0; s < S1_N; s++) {
            const int i1 = __builtin_amdgcn_readlane(idx, 32 + s);
            v1[s] = bf2f(h2bf[i1 * DD + lane]);
        }

        {
            float ea = 0.f, eb = 0.f;
#pragma unroll
            for (int s = 0; s < S0_N; s += 2) {
                ea = fmaf(bcast(w, s),     v0[s],     ea);
                eb = fmaf(bcast(w, s + 1), v0[s + 1], eb);
            }
            float e = (ea + eb) * inv0;
            e = (e > 0.f) ? e : (__expf(e) - 1.f);   // ELU
            e0bf[n * DD + lane] = f2bf(e);
        }
        {
            float ea = 0.f, eb = 0.f, ec = 0.f, ed = 0.f;
#pragma unroll
            for (int s = 0; s < S1_N; s += 4) {
                ea = fmaf(bcast(w, 32 + s), v1[s],     ea);
                eb = fmaf(bcast(w, 33 + s), v1[s + 1], eb);
                ec = fmaf(bcast(w, 34 + s), v1[s + 2], ec);
                ed = fmaf(bcast(w, 35 + s), v1[s + 3], ed);
            }
            float e = ((ea + eb) + (ec + ed)) * inv1;
            e = (e > 0.f) ? e : (__expf(e) - 1.f);
            e1bf[n * DD + lane] = f2bf(e);
        }
    }
}

// Kernel 3: beta reduction via MFMA (validated layout).
__global__ __launch_bounds__(256) void k_beta(
    const unsigned short* __restrict__ e0bf, const unsigned short* __restrict__ e1bf,
    const float* __restrict__ fcw, const float* __restrict__ fcb,
    const float* __restrict__ fus, float* __restrict__ accum)
{
    __shared__ float s_part[2];
    const int tid = threadIdx.x, lane = tid & 63, wid = tid >> 6;
    if (tid < 2) s_part[tid] = 0.f;
    const int m = lane & 15, q = lane >> 4;

    short8 bfr[4][2];
    float fb[4], fu[4];
#pragma unroll
    for (int t = 0; t < 4; t++) {
        const float* wrow = fcw + (t * 16 + m) * DD;
#pragma unroll
        for (int h = 0; h < 2; h++) {
            const float* p = wrow + h * 32 + q * 8;
#pragma unroll
            for (int j = 0; j < 8; j++) bfr[t][h][j] = (short)f2bf(p[j]);
        }
        fb[t] = fcb[t * 16 + m];
        fu[t] = fus[t * 16 + m];
    }
    __syncthreads();

    float rb0 = 0.f, rb1 = 0.f;
    const int gw = blockIdx.x * 4 + wid;
    const int nw = gridDim.x * 4;
    for (int tile = gw; tile < N_NODES / 16; tile += nw) {
        const int rowbase = (tile * 16 + m) * DD + q * 8;
        {
            const short8 a0 = *(const short8*)(e0bf + rowbase);
            const short8 a1 = *(const short8*)(e0bf + rowbase + 32);
            f32x4 c[4];
#pragma unroll
            for (int t = 0; t < 4; t++) {
                c[t] = f32x4{0.f, 0.f, 0.f, 0.f};
                c[t] = __builtin_amdgcn_mfma_f32_16x16x32_bf16(a0, bfr[t][0], c[t], 0, 0, 0);
                c[t] = __builtin_amdgcn_mfma_f32_16x16x32_bf16(a1, bfr[t][1], c[t], 0, 0, 0);
            }
#pragma unroll
            for (int t = 0; t < 4; t++)
#pragma unroll
                for (int j = 0; j < 4; j++)
                    rb0 += tanh_fast(c[t][j] + fb[t]) * fu[t];
        }
        {
            const short8 a0 = *(const short8*)(e1bf + rowbase);
            const short8 a1 = *(const short8*)(e1bf + rowbase + 32);
            f32x4 c[4];
#pragma unroll
            for (int t = 0; t < 4; t++) {
                c[t] = f32x4{0.f, 0.f, 0.f, 0.f};
                c[t] = __builtin_amdgcn_mfma_f32_16x16x32_bf16(a0, bfr[t][0], c[t], 0, 0, 0);
                c[t] = __builtin_amdgcn_mfma_f32_16x16x32_bf16(a1, bfr[t][1], c[t], 0, 0, 0);
            }
#pragma unroll
            for (int t = 0; t < 4; t++)
#pragma unroll
                for (int j = 0; j < 4; j++)
                    rb1 += tanh_fast(c[t][j] + fb[t]) * fu[t];
        }
    }
    const float b0 = wave_sum(rb0);
    const float b1 = wave_sum(rb1);
    if (lane == 0) { atomicAdd(&s_part[0], b0); atomicAdd(&s_part[1], b1); }
    __syncthreads();
    if (tid == 0) { atomicAdd(&accum[0], s_part[0]); atomicAdd(&accum[1], s_part[1]); }
}

// Kernel 4: final elementwise combine.
__global__ __launch_bounds__(256) void k_out(
    const unsigned short* __restrict__ e0bf, const unsigned short* __restrict__ e1bf,
    const float* __restrict__ accum, const float* __restrict__ gate,
    float* __restrict__ out)
{
    const int i = blockIdx.x * 256 + threadIdx.x;
    const float b0 = accum[0] * (1.f / N_NODES);
    const float b1 = accum[1] * (1.f / N_NODES);
    const float mx = fmaxf(b0, b1);
    const float eb0 = __expf(b0 - mx), eb1 = __expf(b1 - mx);
    const float gv  = 1.f / (1.f + __expf(-gate[0]));
    const float c0  = gv * eb0 / (eb0 + eb1);
    const float c1  = gv * eb1 / (eb0 + eb1);
    const float cg  = (1.f - gv) / accum[2];

    const float4 av = ((const float4*)(accum + 4))[i & 15];
    const ushort4 ua = ((const ushort4*)e0bf)[i];
    const ushort4 ub = ((const ushort4*)e1bf)[i];
    float4 o;
    o.x = c0 * bf2f(ua.x) + c1 * bf2f(ub.x) + cg * av.x;
    o.y = c0 * bf2f(ua.y) + c1 * bf2f(ub.y) + cg * av.y;
    o.z = c0 * bf2f(ua.z) + c1 * bf2f(ub.z) + cg * av.z;
    o.w = c0 * bf2f(ua.w) + c1 * bf2f(ub.w) + cg * av.w;
    ((float4*)out)[i] = o;
}

extern "C" void kernel_launch(void* const* d_in, const int* in_sizes, int n_in,
                              void* d_out, int out_size, void* d_ws, size_t ws_size,
                              hipStream_t stream) {
    (void)in_sizes; (void)n_in; (void)out_size; (void)ws_size;
    const float* h0   = (const float*)d_in[0];
    const float* h1   = (const float*)d_in[1];
    const float* h2   = (const float*)d_in[2];
    const int*   nei0 = (const int*)  d_in[3];
    const int*   nei1 = (const int*)  d_in[4];
    const float* aw0  = (const float*)d_in[5];
    const float* aw1  = (const float*)d_in[6];
    const float* fcw  = (const float*)d_in[7];
    const float* fcb  = (const float*)d_in[8];
    const float* fus  = (const float*)d_in[9];
    const float* gatt = (const float*)d_in[10];
    const float* gate = (const float*)d_in[11];
    float* out = (float*)d_out;

    float* ws    = (float*)d_ws;
    float* accum = ws;                               // [0]=b0 [1]=b1 [2]=sumexp [4..67]=wsum
    float* p0r0  = ws + 256;                         // N
    float* p0r1  = p0r0 + N_NODES;                   // N
    float* p1    = p0r1 + N_NODES;                   // M1
    float* p2    = p1 + M1_N;                        // M2
    unsigned short* h1bf = (unsigned short*)(p2 + M2_N);            // M1*64 bf16
    unsigned short* h2bf = h1bf + (size_t)M1_N * DD;                // M2*64 bf16
    unsigned short* e0bf = h2bf + (size_t)M2_N * DD;                // N*64 bf16
    unsigned short* e1bf = e0bf + (size_t)N_NODES * DD;             // N*64 bf16

    hipMemsetAsync(accum, 0, 256 * sizeof(float), stream);
    k_proj<<<1024, 256, 0, stream>>>(h0, h1, h2, aw0, aw1, gatt, accum,
                                     p0r0, p0r1, p1, p2, h1bf, h2bf);
    k_attn<<<2048, 256, 0, stream>>>(h1bf, h2bf, nei0, nei1, p0r0, p0r1, p1, p2, e0bf, e1bf);
    k_beta<<<512, 256, 0, stream>>>(e0bf, e1bf, fcw, fcb, fus, accum);
    k_out<<<(N_NODES * DD / 4) / 256, 256, 0, stream>>>(e0bf, e1bf, accum, gate, out);
}

// Round 6
// 176.921 us; speedup vs baseline: 1.3329x; 1.1560x over previous
//
#include <hip/hip_runtime.h>
#include <math.h>

#define N_NODES 60000
#define M1_N    40000
#define M2_N    40000
#define DD      64
#define S0_N    10
#define S1_N    20
#define R_TOTAL (N_NODES + M1_N + M2_N)
#define T_H0    (N_NODES / 16)              // 3750 tiles
#define T_H1    (T_H0 + M1_N / 16)          // 6250
#define T_ALL   (T_H1 + M2_N / 16)          // 8750
#define PROJ_GRID 1024                      // must equal k_proj launch grid
#define BETA_GRID 512                       // must equal k_beta launch grid

typedef __attribute__((ext_vector_type(8))) short short8;   // 8 bf16 = 4 VGPRs
typedef __attribute__((ext_vector_type(4))) float f32x4;

__device__ __forceinline__ float wave_sum(float x) {
#pragma unroll
    for (int o = 32; o >= 1; o >>= 1) x += __shfl_xor(x, o, 64);
    return x;
}
__device__ __forceinline__ float bcast(float v, int l) {
    return __uint_as_float(__builtin_amdgcn_readlane(__float_as_uint(v), l));
}
__device__ __forceinline__ float tanh_fast(float x) {
    return 1.f - 2.f / (__expf(2.f * x) + 1.f);
}
// f32 -> bf16 round-to-nearest-even
__device__ __forceinline__ unsigned short f2bf(float x) {
    unsigned u = __float_as_uint(x);
    return (unsigned short)((u + 0x7FFFu + ((u >> 16) & 1u)) >> 16);
}
__device__ __forceinline__ float bf2f(unsigned short u) {
    return __uint_as_float(((unsigned)u) << 16);
}

// Kernel 1: projections + global softmax via MFMA. One wave = 16-row tile.
// Epilogue: NON-ATOMIC per-block partial stores (part[j*PROJ_GRID + b]) —
// round-5 showed the contended global atomicAdd tail cost ~35 µs.
__global__ __launch_bounds__(256) void k_proj(
    const float* __restrict__ h0, const float* __restrict__ h1, const float* __restrict__ h2,
    const float* __restrict__ aw0, const float* __restrict__ aw1, const float* __restrict__ gatt,
    float* __restrict__ part,
    float* __restrict__ p0r0, float* __restrict__ p0r1,
    float* __restrict__ p1, float* __restrict__ p2,
    unsigned short* __restrict__ h1bf, unsigned short* __restrict__ h2bf)
{
    __shared__ float s_wsum[64];
    __shared__ float s_se;
    __shared__ float s_es[4][16];
    const int tid = threadIdx.x, lane = tid & 63, wid = tid >> 6;
    if (tid < 64) s_wsum[tid] = 0.f;
    if (tid == 0) s_se = 0.f;
    __syncthreads();

    const int m = lane & 15, quad = lane >> 4;

    // B-frag: col n = m; k = quad*8+j (half0) / 32+quad*8+j (half1)
    short8 b0, b1;
    {
        const float* vsel = 0;
        if (m == 1) vsel = aw0;
        else if (m == 2) vsel = aw1;
        else if (m == 3) vsel = aw0 + DD;
        else if (m == 4) vsel = aw1 + DD;
        else if (m == 0) vsel = gatt;
#pragma unroll
        for (int j = 0; j < 8; j++) {
            b0[j] = vsel ? (short)f2bf(vsel[quad * 8 + j]) : (short)0;
            b1[j] = vsel ? (short)f2bf(vsel[32 + quad * 8 + j]) : (short)0;
        }
    }

    float wacc0[8], wacc1[8];
#pragma unroll
    for (int j = 0; j < 8; j++) { wacc0[j] = 0.f; wacc1[j] = 0.f; }
    float r_se = 0.f;

    const int gw = blockIdx.x * 4 + wid, nw = gridDim.x * 4;
    for (int tile = gw; tile < T_ALL; tile += nw) {
        const float* src; int rbase, region;
        if (tile < T_H0)      { src = h0; rbase = tile * 16;          region = 0; }
        else if (tile < T_H1) { src = h1; rbase = (tile - T_H0) * 16; region = 1; }
        else                  { src = h2; rbase = (tile - T_H1) * 16; region = 2; }
        const int row = rbase + m;
        const float4* rpa = (const float4*)(src + (size_t)row * DD + quad * 8);
        const float4* rpb = (const float4*)(src + (size_t)row * DD + 32 + quad * 8);
        const float4 va = rpa[0], vb = rpa[1];   // dims quad*8 .. quad*8+7
        const float4 vc = rpb[0], vd = rpb[1];   // dims 32+quad*8 .. +7

        short8 a0, a1;
        a0[0] = (short)f2bf(va.x); a0[1] = (short)f2bf(va.y);
        a0[2] = (short)f2bf(va.z); a0[3] = (short)f2bf(va.w);
        a0[4] = (short)f2bf(vb.x); a0[5] = (short)f2bf(vb.y);
        a0[6] = (short)f2bf(vb.z); a0[7] = (short)f2bf(vb.w);
        a1[0] = (short)f2bf(vc.x); a1[1] = (short)f2bf(vc.y);
        a1[2] = (short)f2bf(vc.z); a1[3] = (short)f2bf(vc.w);
        a1[4] = (short)f2bf(vd.x); a1[5] = (short)f2bf(vd.y);
        a1[6] = (short)f2bf(vd.z); a1[7] = (short)f2bf(vd.w);

        f32x4 c = {0.f, 0.f, 0.f, 0.f};
        c = __builtin_amdgcn_mfma_f32_16x16x32_bf16(a0, b0, c, 0, 0, 0);
        c = __builtin_amdgcn_mfma_f32_16x16x32_bf16(a1, b1, c, 0, 0, 0);
        // D[row=quad*4+r][col=m]

        if (m == 0) {        // global-att scores -> es, transposed via LDS
            float4 e4;
            e4.x = __expf(c[0] * 0.125f); e4.y = __expf(c[1] * 0.125f);
            e4.z = __expf(c[2] * 0.125f); e4.w = __expf(c[3] * 0.125f);
            *(float4*)&s_es[wid][quad * 4] = e4;
        }
        __builtin_amdgcn_wave_barrier();   // in-order DS pipe: same-wave write->read safe
        const float es = s_es[wid][m];     // es for this lane's row m
        r_se += es;                         // each row counted 4x (quads); scaled below
        wacc0[0] = fmaf(es, va.x, wacc0[0]); wacc0[1] = fmaf(es, va.y, wacc0[1]);
        wacc0[2] = fmaf(es, va.z, wacc0[2]); wacc0[3] = fmaf(es, va.w, wacc0[3]);
        wacc0[4] = fmaf(es, vb.x, wacc0[4]); wacc0[5] = fmaf(es, vb.y, wacc0[5]);
        wacc0[6] = fmaf(es, vb.z, wacc0[6]); wacc0[7] = fmaf(es, vb.w, wacc0[7]);
        wacc1[0] = fmaf(es, vc.x, wacc1[0]); wacc1[1] = fmaf(es, vc.y, wacc1[1]);
        wacc1[2] = fmaf(es, vc.z, wacc1[2]); wacc1[3] = fmaf(es, vc.w, wacc1[3]);
        wacc1[4] = fmaf(es, vd.x, wacc1[4]); wacc1[5] = fmaf(es, vd.y, wacc1[5]);
        wacc1[6] = fmaf(es, vd.z, wacc1[6]); wacc1[7] = fmaf(es, vd.w, wacc1[7]);

        if (region == 0) {
            if (m == 1) { float4 t = {c[0], c[1], c[2], c[3]}; *(float4*)(p0r0 + rbase + quad * 4) = t; }
            if (m == 2) { float4 t = {c[0], c[1], c[2], c[3]}; *(float4*)(p0r1 + rbase + quad * 4) = t; }
        } else if (region == 1) {
            if (m == 3) { float4 t = {c[0], c[1], c[2], c[3]}; *(float4*)(p1 + rbase + quad * 4) = t; }
            *(short8*)(h1bf + (size_t)row * DD + quad * 8) = a0;
            *(short8*)(h1bf + (size_t)row * DD + 32 + quad * 8) = a1;
        } else {
            if (m == 4) { float4 t = {c[0], c[1], c[2], c[3]}; *(float4*)(p2 + rbase + quad * 4) = t; }
            *(short8*)(h2bf + (size_t)row * DD + quad * 8) = a0;
            *(short8*)(h2bf + (size_t)row * DD + 32 + quad * 8) = a1;
        }
    }

    // block-level reduce into LDS (cheap), then one non-atomic store per slot
    r_se *= 0.25f;
#pragma unroll
    for (int o = 1; o <= 8; o <<= 1) {
#pragma unroll
        for (int j = 0; j < 8; j++) {
            wacc0[j] += __shfl_xor(wacc0[j], o, 64);
            wacc1[j] += __shfl_xor(wacc1[j], o, 64);
        }
    }
    if (m == 0) {
#pragma unroll
        for (int j = 0; j < 8; j++) {
            atomicAdd(&s_wsum[quad * 8 + j],      wacc0[j]);   // LDS atomic: cheap
            atomicAdd(&s_wsum[32 + quad * 8 + j], wacc1[j]);
        }
    }
    const float se = wave_sum(r_se);
    if (lane == 0) atomicAdd(&s_se, se);
    __syncthreads();
    if (tid < 64) part[tid * PROJ_GRID + blockIdx.x] = s_wsum[tid];
    if (tid == 64) part[64 * PROJ_GRID + blockIdx.x] = s_se;
}

// Kernel 2: per-node neighbor attention (unchanged from round 5).
__global__ __launch_bounds__(256) void k_attn(
    const unsigned short* __restrict__ h1bf, const unsigned short* __restrict__ h2bf,
    const int* __restrict__ nei0, const int* __restrict__ nei1,
    const float* __restrict__ p0r0, const float* __restrict__ p0r1,
    const float* __restrict__ p1, const float* __restrict__ p2,
    unsigned short* __restrict__ e0bf, unsigned short* __restrict__ e1bf)
{
    const int tid = threadIdx.x, lane = tid & 63, wid = tid >> 6;
    const bool grp0 = (lane < S0_N);
    const bool grp1 = (lane >= 32) && (lane < 32 + S1_N);
    const int gw = blockIdx.x * 4 + wid;
    const int nw = gridDim.x * 4;
    for (int n = gw; n < N_NODES; n += nw) {
        const float pr0 = p0r0[n];
        const float pr1 = p0r1[n];

        int idx = 0; float w = 0.f;
        if (grp0) idx = nei0[n * S0_N + lane];
        if (grp1) idx = nei1[n * S1_N + (lane - 32)];
        if (grp0 | grp1) {
            float t = (grp0 ? pr0 : pr1) + (grp0 ? p1[idx] : p2[idx]);
            t = (t >= 0.f) ? t : 0.01f * t;      // leaky_relu(0.01)
            w = __expf(t);                        // scores bounded; no max-sub
        }
        float sv = w;
#pragma unroll
        for (int o = 16; o >= 1; o >>= 1) sv += __shfl_xor(sv, o, 64);
        const float inv0 = 1.f / bcast(sv, 0);
        const float inv1 = 1.f / bcast(sv, 32);

        float v0[S0_N], v1[S1_N];
#pragma unroll
        for (int s = 0; s < S0_N; s++) {
            const int i0 = __builtin_amdgcn_readlane(idx, s);
            v0[s] = bf2f(h1bf[i0 * DD + lane]);
        }
#pragma unroll
        for (int s = 0; s < S1_N; s++) {
            const int i1 = __builtin_amdgcn_readlane(idx, 32 + s);
            v1[s] = bf2f(h2bf[i1 * DD + lane]);
        }

        {
            float ea = 0.f, eb = 0.f;
#pragma unroll
            for (int s = 0; s < S0_N; s += 2) {
                ea = fmaf(bcast(w, s),     v0[s],     ea);
                eb = fmaf(bcast(w, s + 1), v0[s + 1], eb);
            }
            float e = (ea + eb) * inv0;
            e = (e > 0.f) ? e : (__expf(e) - 1.f);   // ELU
            e0bf[n * DD + lane] = f2bf(e);
        }
        {
            float ea = 0.f, eb = 0.f, ec = 0.f, ed = 0.f;
#pragma unroll
            for (int s = 0; s < S1_N; s += 4) {
                ea = fmaf(bcast(w, 32 + s), v1[s],     ea);
                eb = fmaf(bcast(w, 33 + s), v1[s + 1], eb);
                ec = fmaf(bcast(w, 34 + s), v1[s + 2], ec);
                ed = fmaf(bcast(w, 35 + s), v1[s + 3], ed);
            }
            float e = ((ea + eb) + (ec + ed)) * inv1;
            e = (e > 0.f) ? e : (__expf(e) - 1.f);
            e1bf[n * DD + lane] = f2bf(e);
        }
    }
}

// Kernel 3: beta reduction via MFMA; epilogue now stores per-block partials
// (bpart[b], bpart[BETA_GRID+b]) instead of contended global atomics.
__global__ __launch_bounds__(256) void k_beta(
    const unsigned short* __restrict__ e0bf, const unsigned short* __restrict__ e1bf,
    const float* __restrict__ fcw, const float* __restrict__ fcb,
    const float* __restrict__ fus, float* __restrict__ bpart)
{
    __shared__ float s_part[2];
    const int tid = threadIdx.x, lane = tid & 63, wid = tid >> 6;
    if (tid < 2) s_part[tid] = 0.f;
    const int m = lane & 15, q = lane >> 4;

    short8 bfr[4][2];
    float fb[4], fu[4];
#pragma unroll
    for (int t = 0; t < 4; t++) {
        const float* wrow = fcw + (t * 16 + m) * DD;
#pragma unroll
        for (int h = 0; h < 2; h++) {
            const float* p = wrow + h * 32 + q * 8;
#pragma unroll
            for (int j = 0; j < 8; j++) bfr[t][h][j] = (short)f2bf(p[j]);
        }
        fb[t] = fcb[t * 16 + m];
        fu[t] = fus[t * 16 + m];
    }
    __syncthreads();

    float rb0 = 0.f, rb1 = 0.f;
    const int gw = blockIdx.x * 4 + wid;
    const int nw = gridDim.x * 4;
    for (int tile = gw; tile < N_NODES / 16; tile += nw) {
        const int rowbase = (tile * 16 + m) * DD + q * 8;
        {
            const short8 a0 = *(const short8*)(e0bf + rowbase);
            const short8 a1 = *(const short8*)(e0bf + rowbase + 32);
            f32x4 c[4];
#pragma unroll
            for (int t = 0; t < 4; t++) {
                c[t] = f32x4{0.f, 0.f, 0.f, 0.f};
                c[t] = __builtin_amdgcn_mfma_f32_16x16x32_bf16(a0, bfr[t][0], c[t], 0, 0, 0);
                c[t] = __builtin_amdgcn_mfma_f32_16x16x32_bf16(a1, bfr[t][1], c[t], 0, 0, 0);
            }
#pragma unroll
            for (int t = 0; t < 4; t++)
#pragma unroll
                for (int j = 0; j < 4; j++)
                    rb0 += tanh_fast(c[t][j] + fb[t]) * fu[t];
        }
        {
            const short8 a0 = *(const short8*)(e1bf + rowbase);
            const short8 a1 = *(const short8*)(e1bf + rowbase + 32);
            f32x4 c[4];
#pragma unroll
            for (int t = 0; t < 4; t++) {
                c[t] = f32x4{0.f, 0.f, 0.f, 0.f};
                c[t] = __builtin_amdgcn_mfma_f32_16x16x32_bf16(a0, bfr[t][0], c[t], 0, 0, 0);
                c[t] = __builtin_amdgcn_mfma_f32_16x16x32_bf16(a1, bfr[t][1], c[t], 0, 0, 0);
            }
#pragma unroll
            for (int t = 0; t < 4; t++)
#pragma unroll
                for (int j = 0; j < 4; j++)
                    rb1 += tanh_fast(c[t][j] + fb[t]) * fu[t];
        }
    }
    const float b0 = wave_sum(rb0);
    const float b1 = wave_sum(rb1);
    if (lane == 0) { atomicAdd(&s_part[0], b0); atomicAdd(&s_part[1], b1); }   // LDS
    __syncthreads();
    if (tid == 0) {
        bpart[blockIdx.x]             = s_part[0];
        bpart[BETA_GRID + blockIdx.x] = s_part[1];
    }
}

// Kernel 3.5: single-block reduction of all partials -> accum.
// Wave w handles rows j = w, w+4, ...; coalesced reads of part[j*PROJ_GRID+..].
__global__ __launch_bounds__(256) void k_reduce(
    const float* __restrict__ part, const float* __restrict__ bpart,
    float* __restrict__ accum)
{
    const int tid = threadIdx.x, lane = tid & 63, wid = tid >> 6;
    if (wid == 0) {   // beta partials: 2 rows of BETA_GRID
        float t0 = 0.f, t1 = 0.f;
#pragma unroll
        for (int k = 0; k < BETA_GRID / 64; k++) {
            t0 += bpart[lane + 64 * k];
            t1 += bpart[BETA_GRID + lane + 64 * k];
        }
        t0 = wave_sum(t0); t1 = wave_sum(t1);
        if (lane == 0) { accum[0] = t0; accum[1] = t1; }
    }
    for (int j = wid; j < 65; j += 4) {
        float s = 0.f;
#pragma unroll
        for (int k = 0; k < PROJ_GRID / 64; k++)
            s += part[j * PROJ_GRID + lane + 64 * k];
        s = wave_sum(s);
        if (lane == 0) {
            if (j < 64) accum[4 + j] = s;
            else        accum[2] = s;
        }
    }
}

// Kernel 4: final elementwise combine.
__global__ __launch_bounds__(256) void k_out(
    const unsigned short* __restrict__ e0bf, const unsigned short* __restrict__ e1bf,
    const float* __restrict__ accum, const float* __restrict__ gate,
    float* __restrict__ out)
{
    const int i = blockIdx.x * 256 + threadIdx.x;
    const float b0 = accum[0] * (1.f / N_NODES);
    const float b1 = accum[1] * (1.f / N_NODES);
    const float mx = fmaxf(b0, b1);
    const float eb0 = __expf(b0 - mx), eb1 = __expf(b1 - mx);
    const float gv  = 1.f / (1.f + __expf(-gate[0]));
    const float c0  = gv * eb0 / (eb0 + eb1);
    const float c1  = gv * eb1 / (eb0 + eb1);
    const float cg  = (1.f - gv) / accum[2];

    const float4 av = ((const float4*)(accum + 4))[i & 15];
    const ushort4 ua = ((const ushort4*)e0bf)[i];
    const ushort4 ub = ((const ushort4*)e1bf)[i];
    float4 o;
    o.x = c0 * bf2f(ua.x) + c1 * bf2f(ub.x) + cg * av.x;
    o.y = c0 * bf2f(ua.y) + c1 * bf2f(ub.y) + cg * av.y;
    o.z = c0 * bf2f(ua.z) + c1 * bf2f(ub.z) + cg * av.z;
    o.w = c0 * bf2f(ua.w) + c1 * bf2f(ub.w) + cg * av.w;
    ((float4*)out)[i] = o;
}

extern "C" void kernel_launch(void* const* d_in, const int* in_sizes, int n_in,
                              void* d_out, int out_size, void* d_ws, size_t ws_size,
                              hipStream_t stream) {
    (void)in_sizes; (void)n_in; (void)out_size; (void)ws_size;
    const float* h0   = (const float*)d_in[0];
    const float* h1   = (const float*)d_in[1];
    const float* h2   = (const float*)d_in[2];
    const int*   nei0 = (const int*)  d_in[3];
    const int*   nei1 = (const int*)  d_in[4];
    const float* aw0  = (const float*)d_in[5];
    const float* aw1  = (const float*)d_in[6];
    const float* fcw  = (const float*)d_in[7];
    const float* fcb  = (const float*)d_in[8];
    const float* fus  = (const float*)d_in[9];
    const float* gatt = (const float*)d_in[10];
    const float* gate = (const float*)d_in[11];
    float* out = (float*)d_out;

    float* ws    = (float*)d_ws;
    float* accum = ws;                               // [0]=b0 [1]=b1 [2]=sumexp [4..67]=wsum
    float* p0r0  = ws + 256;                         // N
    float* p0r1  = p0r0 + N_NODES;                   // N
    float* p1    = p0r1 + N_NODES;                   // M1
    float* p2    = p1 + M1_N;                        // M2
    unsigned short* h1bf = (unsigned short*)(p2 + M2_N);            // M1*64 bf16
    unsigned short* h2bf = h1bf + (size_t)M1_N * DD;                // M2*64 bf16
    unsigned short* e0bf = h2bf + (size_t)M2_N * DD;                // N*64 bf16
    unsigned short* e1bf = e0bf + (size_t)N_NODES * DD;             // N*64 bf16
    float* part  = (float*)(e1bf + (size_t)N_NODES * DD);           // 65*PROJ_GRID
    float* bpart = part + 65 * PROJ_GRID;                           // 2*BETA_GRID
    // all partial slots are written unconditionally -> no zeroing needed

    k_proj<<<PROJ_GRID, 256, 0, stream>>>(h0, h1, h2, aw0, aw1, gatt, part,
                                          p0r0, p0r1, p1, p2, h1bf, h2bf);
    k_attn<<<2048, 256, 0, stream>>>(h1bf, h2bf, nei0, nei1, p0r0, p0r1, p1, p2, e0bf, e1bf);
    k_beta<<<BETA_GRID, 256, 0, stream>>>(e0bf, e1bf, fcw, fcb, fus, bpart);
    k_reduce<<<1, 256, 0, stream>>>(part, bpart, accum);
    k_out<<<(N_NODES * DD / 4) / 256, 256, 0, stream>>>(e0bf, e1bf, accum, gate, out);
}